// Round 17
// baseline (108.869 us; speedup 1.0000x reference)
//
#include <hip/hip_runtime.h>
#include <stdint.h>

// Depthwise 7x7 VALID conv, fp32, NCHW.
// x: (16,256,128,128), w: (256,7,7), out: (16,256,122,122)
// R15 DMA column sweep (7-pair-deep pipeline), SINGLE CHANGE vs R15:
// plain cacheable stores instead of nontemporal. vmcnt retires in issue
// order, so counted WAITV(N) implicitly waits on stores issued >=7 steps
// ago; nt stores (L2-bypass, partial-line RMW at DRAM) make that ack
// slow. Plain stores ack at L2 and let L2 merge the 488B rows.
//  - block = one image, 4 waves = 4 row-quarters (r0 = 30q, 38-row sweep).
//  - wave-private LDS ring: 8 slots x 2 rows x 128 floats (8 KB/wave).
//  - counted vmcnt (never 0); 8-slot compile-time accumulator ring.
//  - weights in SGPRs (readfirstlane); no launch_bounds min-waves hint.

#define BATCH 16
#define CHAN  256
#define H_IN  128
#define W_IN  128
#define KS    7
#define H_OUT 122
#define W_OUT 122

typedef float v2f __attribute__((ext_vector_type(2)));

__device__ __forceinline__ float sgpr_bcast(float v) {
    return __int_as_float(__builtin_amdgcn_readfirstlane(__float_as_int(v)));
}

__global__ __launch_bounds__(256)
void dwconv7x7_kernel(const float* __restrict__ x,
                      const float* __restrict__ w,
                      float* __restrict__ out) {
    __shared__ float lds[4][8][256];   // [wave][slot][2 rows x 128 floats]

    const int lane = threadIdx.x & 63;
    const int q    = threadIdx.x >> 6;           // row-quarter 0..3
    const int img  = blockIdx.x;                 // b*CHAN + c
    const int ch   = img & (CHAN - 1);

    int c = 2 * lane;                 // lanes 0..31 -> cols 0..62
    if (lane >= 32) c -= 6;           // lanes 32..63 -> cols 58..120
    const int r0 = 30 * q;            // sweep input rows r0..r0+37

    // ---- weights: block-uniform -> force into SGPRs ----
    const float* __restrict__ wp = w + ch * (KS * KS);
    float wr[KS * KS];
    #pragma unroll
    for (int i = 0; i < KS * KS; ++i) wr[i] = sgpr_bcast(wp[i]);

    // per-lane DMA source (16B/lane; 64 lanes = 2 rows of 128 floats)
    const float* xstage =
        x + (size_t)img * (H_IN * W_IN) + (size_t)r0 * W_IN + lane * 4;
    float* oq =
        out + (size_t)img * (H_OUT * W_OUT) + (size_t)r0 * W_OUT + c;

    v2f acc[8];                       // ring: slot = (local output row) & 7
    #pragma unroll
    for (int i = 0; i < 8; ++i) { acc[i].x = 0.f; acc[i].y = 0.f; }

    // fence first so vmem issue order is pinned (vmcnt counts depend on it)
    #define STAGE(SLOT) do {                                               \
        asm volatile("" ::: "memory");                                     \
        __builtin_amdgcn_global_load_lds(                                  \
            (const __attribute__((address_space(1))) void*)xstage,         \
            (__attribute__((address_space(3))) void*)&lds[q][SLOT][0],     \
            16, 0, 0);                                                     \
        xstage += 2 * W_IN; } while (0)

    #define WAITV(N) asm volatile("s_waitcnt vmcnt(" #N ")" ::: "memory")

    // one input row: 4x ds_read_b64 window + packed FMA into acc ring
    #define ROWD(SM8, LSLOT, HALF, KYLO, KYHI) do {                        \
        const float* rl = &lds[q][LSLOT][(HALF) * 128];                    \
        const v2f p0 = *(const v2f*)(rl + c);                              \
        const v2f p1 = *(const v2f*)(rl + c + 2);                          \
        const v2f p2 = *(const v2f*)(rl + c + 4);                          \
        const v2f p3 = *(const v2f*)(rl + c + 6);                          \
        v2f s0, s1, s2;                                                    \
        s0.x = p0.y; s0.y = p1.x;                                          \
        s1.x = p1.y; s1.y = p2.x;                                          \
        s2.x = p2.y; s2.y = p3.x;                                          \
        const v2f srcv[7] = {p0, s0, p1, s1, p2, s2, p3};                  \
        _Pragma("unroll")                                                  \
        for (int ky = (KYLO); ky <= (KYHI); ++ky) {                        \
            _Pragma("unroll")                                              \
            for (int kx = 0; kx < 7; ++kx) {                               \
                const float wv = wr[ky * 7 + kx];                          \
                v2f wpair; wpair.x = wv; wpair.y = wv;                     \
                acc[((SM8) - ky + 8) & 7] = __builtin_elementwise_fma(     \
                    srcv[kx], wpair, acc[((SM8) - ky + 8) & 7]);           \
            }                                                              \
        } } while (0)

    #define ST(OSLOT) do {                                                 \
        *(v2f*)oq = acc[OSLOT];                                            \
        acc[OSLOT].x = 0.f; acc[OSLOT].y = 0.f;                           \
        oq += W_OUT; } while (0)

    // ---- prologue staging: pairs 0..6 -> slots 0..6 ----
    STAGE(0); STAGE(1); STAGE(2); STAGE(3); STAGE(4); STAGE(5); STAGE(6);

    // m=0..2: rows 0..5 (partial ky), no stores yet
    STAGE(7); WAITV(7);
    ROWD(0, 0, 0, 0, 0);
    ROWD(1, 0, 1, 0, 1);
    STAGE(0); WAITV(7);
    ROWD(2, 1, 0, 0, 2);
    ROWD(3, 1, 1, 0, 3);
    STAGE(1); WAITV(7);
    ROWD(4, 2, 0, 0, 4);
    ROWD(5, 2, 1, 0, 5);
    // m=3: rows 6,7; stores begin (o=0,1)
    STAGE(2); WAITV(7);
    ROWD(6, 3, 0, 0, 6); ST(0);
    ROWD(7, 3, 1, 0, 6); ST(1);
    // m=4..6: ramp-up waits
    STAGE(3); WAITV(9);
    ROWD(0, 4, 0, 0, 6); ST(2);
    ROWD(1, 4, 1, 0, 6); ST(3);
    STAGE(4); WAITV(11);
    ROWD(2, 5, 0, 0, 6); ST(4);
    ROWD(3, 5, 1, 0, 6); ST(5);
    STAGE(5); WAITV(13);
    ROWD(4, 6, 0, 0, 6); ST(6);
    ROWD(5, 6, 1, 0, 6); ST(7);
    // m=7..9
    STAGE(6); WAITV(15);
    ROWD(6, 7, 0, 0, 6); ST(0);
    ROWD(7, 7, 1, 0, 6); ST(1);
    STAGE(7); WAITV(17);
    ROWD(0, 0, 0, 0, 6); ST(2);
    ROWD(1, 0, 1, 0, 6); ST(3);
    STAGE(0); WAITV(19);
    ROWD(2, 1, 0, 0, 6); ST(4);
    ROWD(3, 1, 1, 0, 6); ST(5);
    // m=10,11: steady waits
    STAGE(1); WAITV(21);
    ROWD(4, 2, 0, 0, 6); ST(6);
    ROWD(5, 2, 1, 0, 6); ST(7);
    STAGE(2); WAITV(21);
    ROWD(6, 3, 0, 0, 6); ST(0);
    ROWD(7, 3, 1, 0, 6); ST(1);
    // m=12..15: drain (no more stages), decreasing counted waits
    WAITV(20);
    ROWD(0, 4, 0, 0, 6); ST(2);
    ROWD(1, 4, 1, 0, 6); ST(3);
    WAITV(19);
    ROWD(2, 5, 0, 0, 6); ST(4);
    ROWD(3, 5, 1, 0, 6); ST(5);
    WAITV(18);
    ROWD(4, 6, 0, 0, 6); ST(6);
    ROWD(5, 6, 1, 0, 6); ST(7);
    WAITV(17);
    ROWD(6, 7, 0, 0, 6); ST(0);
    ROWD(7, 7, 1, 0, 6); ST(1);
    // m=16..18: rows 32..37, ky truncated (outputs capped at o=31)
    WAITV(16);
    ROWD(0, 0, 0, 1, 6); ST(2);
    ROWD(1, 0, 1, 2, 6); ST(3);
    WAITV(15);
    ROWD(2, 1, 0, 3, 6); ST(4);
    ROWD(3, 1, 1, 4, 6); ST(5);
    WAITV(14);
    ROWD(4, 2, 0, 5, 6); ST(6);
    ROWD(5, 2, 1, 6, 6); ST(7);

    #undef STAGE
    #undef WAITV
    #undef ROWD
    #undef ST
}

extern "C" void kernel_launch(void* const* d_in, const int* in_sizes, int n_in,
                              void* d_out, int out_size, void* d_ws, size_t ws_size,
                              hipStream_t stream) {
    const float* x = (const float*)d_in[0];
    const float* w = (const float*)d_in[1];
    float* out = (float*)d_out;

    // one block per image; 4 waves = 4 row-quarters
    dim3 grid(BATCH * CHAN, 1, 1);   // 4096 blocks
    dim3 block(256, 1, 1);
    dwconv7x7_kernel<<<grid, block, 0, stream>>>(x, w, out);
}

// Round 18
// 98.377 us; speedup vs baseline: 1.1067x; 1.1067x over previous
//
#include <hip/hip_runtime.h>
#include <stdint.h>

// Depthwise 7x7 VALID conv, fp32, NCHW.
// x: (16,256,128,128), w: (256,7,7), out: (16,256,122,122)
// R13 DMA column sweep, quarters -> HALVES (70-row sweep, 64 output rows
// per wave): read-halo dup drops 152->140 rows/image; steady state 26 of
// 35 steps (vs 9 of 19). Everything else = R13: wave-private 4-slot LDS
// ring (2 rows/slot), stage 3 pairs ahead, counted vmcnt (never 0, exact),
// packed v_pk_fma via v2f, 8-slot compile-time acc ring, nontemporal
// stores (R16: plain stores thrash L2/L3 input residency, +14us),
// weights in SGPRs via readfirstlane, no launch_bounds min-waves hint.
// Block = 256 thr = 4 waves = 2 images x 2 halves; grid 2048.
// lanes 0-31: col pair c=2*lane (cols 0..63); lanes 32-63: c=2*lane-6
// (cols 58..121, 3-pair overlap benign). h=1 re-stores rows 58..63 of the
// image (identical values) - unconditional stores keep vmcnt wave-uniform.

#define BATCH 16
#define CHAN  256
#define H_IN  128
#define W_IN  128
#define KS    7
#define H_OUT 122
#define W_OUT 122

typedef float v2f __attribute__((ext_vector_type(2)));

__device__ __forceinline__ float sgpr_bcast(float v) {
    return __int_as_float(__builtin_amdgcn_readfirstlane(__float_as_int(v)));
}

__global__ __launch_bounds__(256)
void dwconv7x7_kernel(const float* __restrict__ x,
                      const float* __restrict__ w,
                      float* __restrict__ out) {
    __shared__ float lds[4][4][256];   // [wave][slot][2 rows x 128 floats]

    const int lane = threadIdx.x & 63;
    const int wv   = threadIdx.x >> 6;           // wave in block 0..3
    const int unit = blockIdx.x * 4 + wv;        // (img, half)
    const int img  = unit >> 1;                  // b*CHAN + c
    const int h    = unit & 1;                   // row-half 0/1
    const int ch   = img & (CHAN - 1);

    int c = 2 * lane;                 // lanes 0..31 -> cols 0..62
    if (lane >= 32) c -= 6;           // lanes 32..63 -> cols 58..120
    const int r0 = h ? (H_IN - 70) : 0;   // 0 or 58; sweep rows r0..r0+69

    // ---- weights: block-uniform -> force into SGPRs ----
    const float* __restrict__ wp = w + ch * (KS * KS);
    float wr[KS * KS];
    #pragma unroll
    for (int i = 0; i < KS * KS; ++i) wr[i] = sgpr_bcast(wp[i]);

    // per-lane DMA source (16B/lane; 64 lanes = 2 rows of 128 floats)
    const float* xstage =
        x + (size_t)img * (H_IN * W_IN) + (size_t)r0 * W_IN + lane * 4;
    float* oq =
        out + (size_t)img * (H_OUT * W_OUT) + (size_t)r0 * W_OUT + c;

    v2f acc[8];                       // ring: slot = (local output row) & 7
    #pragma unroll
    for (int i = 0; i < 8; ++i) { acc[i].x = 0.f; acc[i].y = 0.f; }

    // fence first so vmem issue order is pinned (vmcnt counts depend on it)
    #define STAGE(SLOT) do {                                               \
        asm volatile("" ::: "memory");                                     \
        __builtin_amdgcn_global_load_lds(                                  \
            (const __attribute__((address_space(1))) void*)xstage,         \
            (__attribute__((address_space(3))) void*)&lds[wv][SLOT][0],    \
            16, 0, 0);                                                     \
        xstage += 2 * W_IN; } while (0)

    #define WAITV(N) asm volatile("s_waitcnt vmcnt(" #N ")" ::: "memory")

    // one input row: 4x ds_read_b64 window + packed FMA into acc ring
    #define ROWD(SM8, LSLOT, HALF, KYLO, KYHI) do {                        \
        const float* rl = &lds[wv][LSLOT][(HALF) * 128];                   \
        const v2f p0 = *(const v2f*)(rl + c);                              \
        const v2f p1 = *(const v2f*)(rl + c + 2);                          \
        const v2f p2 = *(const v2f*)(rl + c + 4);                          \
        const v2f p3 = *(const v2f*)(rl + c + 6);                          \
        v2f s0, s1, s2;                                                    \
        s0.x = p0.y; s0.y = p1.x;                                          \
        s1.x = p1.y; s1.y = p2.x;                                          \
        s2.x = p2.y; s2.y = p3.x;                                          \
        const v2f srcv[7] = {p0, s0, p1, s1, p2, s2, p3};                  \
        _Pragma("unroll")                                                  \
        for (int ky = (KYLO); ky <= (KYHI); ++ky) {                        \
            _Pragma("unroll")                                              \
            for (int kx = 0; kx < 7; ++kx) {                               \
                const float wv_ = wr[ky * 7 + kx];                         \
                v2f wpair; wpair.x = wv_; wpair.y = wv_;                   \
                acc[((SM8) - ky + 8) & 7] = __builtin_elementwise_fma(     \
                    srcv[kx], wpair, acc[((SM8) - ky + 8) & 7]);           \
            }                                                              \
        } } while (0)

    #define ST(OSLOT) do {                                                 \
        __builtin_nontemporal_store(acc[OSLOT], (v2f*)oq);                 \
        acc[OSLOT].x = 0.f; acc[OSLOT].y = 0.f;                           \
        oq += W_OUT; } while (0)

    // ---- prologue staging: pairs 0,1,2 -> slots 0,1,2 ----
    STAGE(0); STAGE(1); STAGE(2);

    // m=0..2: rows 0..5 (partial ky), no stores
    STAGE(3); WAITV(3);               // pair 3
    ROWD(0, 0, 0, 0, 0);
    ROWD(1, 0, 1, 0, 1);
    STAGE(0); WAITV(3);               // pair 4
    ROWD(2, 1, 0, 0, 2);
    ROWD(3, 1, 1, 0, 3);
    STAGE(1); WAITV(3);               // pair 5
    ROWD(4, 2, 0, 0, 4);
    ROWD(5, 2, 1, 0, 5);
    // m=3: rows 6,7; stores begin (o=0,1)
    STAGE(2); WAITV(3);               // pair 6
    ROWD(6, 3, 0, 0, 6); ST(0);
    ROWD(7, 3, 1, 0, 6); ST(1);
    // m=4,5: ramp (exact counts)
    STAGE(3); WAITV(5);               // pair 7
    ROWD(0, 0, 0, 0, 6); ST(2);
    ROWD(1, 0, 1, 0, 6); ST(3);
    STAGE(0); WAITV(7);               // pair 8
    ROWD(2, 1, 0, 0, 6); ST(4);
    ROWD(3, 1, 1, 0, 6); ST(5);

    // ---- steady: m=6..29 (6 reps x 4 steps), WAITV(9) counted ----
    for (int rep = 0; rep < 6; ++rep) {
        STAGE(1); WAITV(9);
        ROWD(4, 2, 0, 0, 6); ST(6);
        ROWD(5, 2, 1, 0, 6); ST(7);
        STAGE(2); WAITV(9);
        ROWD(6, 3, 0, 0, 6); ST(0);
        ROWD(7, 3, 1, 0, 6); ST(1);
        STAGE(3); WAITV(9);
        ROWD(0, 0, 0, 0, 6); ST(2);
        ROWD(1, 0, 1, 0, 6); ST(3);
        STAGE(0); WAITV(9);
        ROWD(2, 1, 0, 0, 6); ST(4);
        ROWD(3, 1, 1, 0, 6); ST(5);
    }

    // m=30,31: last stages (pairs 33,34)
    STAGE(1); WAITV(9);
    ROWD(4, 2, 0, 0, 6); ST(6);
    ROWD(5, 2, 1, 0, 6); ST(7);
    STAGE(2); WAITV(9);
    ROWD(6, 3, 0, 0, 6); ST(0);
    ROWD(7, 3, 1, 0, 6); ST(1);
    // m=32..34: drain, rows 64..69 ky-truncated (outputs end at o=63)
    WAITV(8);
    ROWD(0, 0, 0, 1, 6); ST(2);
    ROWD(1, 0, 1, 2, 6); ST(3);
    WAITV(7);
    ROWD(2, 1, 0, 3, 6); ST(4);
    ROWD(3, 1, 1, 4, 6); ST(5);
    WAITV(6);
    ROWD(4, 2, 0, 5, 6); ST(6);
    ROWD(5, 2, 1, 6, 6); ST(7);

    #undef STAGE
    #undef WAITV
    #undef ROWD
    #undef ST
}

extern "C" void kernel_launch(void* const* d_in, const int* in_sizes, int n_in,
                              void* d_out, int out_size, void* d_ws, size_t ws_size,
                              hipStream_t stream) {
    const float* x = (const float*)d_in[0];
    const float* w = (const float*)d_in[1];
    float* out = (float*)d_out;

    // block = 4 waves = 2 images x 2 halves
    dim3 grid(BATCH * CHAN / 2, 1, 1);   // 2048 blocks
    dim3 block(256, 1, 1);
    dwconv7x7_kernel<<<grid, block, 0, stream>>>(x, w, out);
}

// Round 19
// 93.723 us; speedup vs baseline: 1.1616x; 1.0497x over previous
//
#include <hip/hip_runtime.h>
#include <stdint.h>

// Depthwise 7x7 VALID conv, fp32, NCHW.  (R13 — best measured: 94.2 us)
// x: (16,256,128,128), w: (256,7,7), out: (16,256,122,122)
// DMA-pipelined column sweep:
//  - block = one image, 4 waves = 4 row-quarters (r0 = 30q, 38-row sweep,
//    32 output rows; q>0 skips its first 2 duplicate row stores).
//  - lanes 0-31: col pair c=2*lane; lanes 32-63: c=2*lane-6 (dup cols benign).
//  - wave-private LDS ring: 4 slots x 2 rows x 128 floats (1 KB/slot).
//    Each macro-step: 1 global_load_lds (64 lanes x 16B = 2 rows) staged
//    3 pairs ahead, counted s_waitcnt vmcnt(N) (never 0), then 2 rows of
//    4x ds_read_b64 window + 49 packed FMA + 1 store each.
//  - 8-slot accumulator ring (v2f acc[8]) -> ALL indices compile-time.
//  - empty asm memory fences pin VMEM issue order so vmcnt counts are exact.
//  - no launch_bounds min-waves hint (R2/R5/R7: triggers scratch demotion).

#define BATCH 16
#define CHAN  256
#define H_IN  128
#define W_IN  128
#define KS    7
#define H_OUT 122
#define W_OUT 122

typedef float v2f __attribute__((ext_vector_type(2)));

__device__ __forceinline__ float sgpr_bcast(float v) {
    return __int_as_float(__builtin_amdgcn_readfirstlane(__float_as_int(v)));
}

__global__ __launch_bounds__(256)
void dwconv7x7_kernel(const float* __restrict__ x,
                      const float* __restrict__ w,
                      float* __restrict__ out) {
    __shared__ float lds[4][4][256];   // [wave][slot][2 rows x 128 floats]

    const int lane = threadIdx.x & 63;
    const int q    = threadIdx.x >> 6;           // row-quarter 0..3
    const int img  = blockIdx.x;                 // b*CHAN + c
    const int ch   = img & (CHAN - 1);

    int c = 2 * lane;                 // lanes 0..31 -> cols 0..62
    if (lane >= 32) c -= 6;           // lanes 32..63 -> cols 58..120
    const int r0 = 30 * q;            // sweep input rows r0..r0+37

    // ---- weights: block-uniform -> force into SGPRs ----
    const float* __restrict__ wp = w + ch * (KS * KS);
    float wr[KS * KS];
    #pragma unroll
    for (int i = 0; i < KS * KS; ++i) wr[i] = sgpr_bcast(wp[i]);

    // per-lane global source pointer for DMA staging (16B per lane = 4 floats;
    // 64 lanes cover exactly 2 rows of 128 floats, contiguous in memory)
    const float* xstage =
        x + (size_t)img * (H_IN * W_IN) + (size_t)r0 * W_IN + lane * 4;
    float* oq =
        out + (size_t)img * (H_OUT * W_OUT) + (size_t)r0 * W_OUT + c;

    v2f acc[8];                       // ring: slot = (local output row) % 8
    #pragma unroll
    for (int i = 0; i < 8; ++i) { acc[i].x = 0.f; acc[i].y = 0.f; }

    // fence first so stage order is pinned (vmcnt counts depend on it)
    #define STAGE(SLOT) do {                                               \
        asm volatile("" ::: "memory");                                     \
        __builtin_amdgcn_global_load_lds(                                  \
            (const __attribute__((address_space(1))) void*)xstage,         \
            (__attribute__((address_space(3))) void*)&lds[q][SLOT][0],     \
            16, 0, 0);                                                     \
        xstage += 2 * W_IN; } while (0)

    #define WAITV(N) asm volatile("s_waitcnt vmcnt(" #N ")" ::: "memory")

    // one input row: 4x ds_read_b64 window + packed FMA into acc ring
    #define ROWD(SM8, LSLOT, HALF, KYLO, KYHI) do {                        \
        const float* rl = &lds[q][LSLOT][(HALF) * 128];                    \
        const v2f p0 = *(const v2f*)(rl + c);                              \
        const v2f p1 = *(const v2f*)(rl + c + 2);                          \
        const v2f p2 = *(const v2f*)(rl + c + 4);                          \
        const v2f p3 = *(const v2f*)(rl + c + 6);                          \
        v2f s0, s1, s2;                                                    \
        s0.x = p0.y; s0.y = p1.x;                                          \
        s1.x = p1.y; s1.y = p2.x;                                          \
        s2.x = p2.y; s2.y = p3.x;                                          \
        const v2f srcv[7] = {p0, s0, p1, s1, p2, s2, p3};                  \
        _Pragma("unroll")                                                  \
        for (int ky = (KYLO); ky <= (KYHI); ++ky) {                        \
            _Pragma("unroll")                                              \
            for (int kx = 0; kx < 7; ++kx) {                               \
                const float wv = wr[ky * 7 + kx];                          \
                v2f wpair; wpair.x = wv; wpair.y = wv;                     \
                acc[((SM8) - ky + 8) & 7] = __builtin_elementwise_fma(     \
                    srcv[kx], wpair, acc[((SM8) - ky + 8) & 7]);           \
            }                                                              \
        } } while (0)

    #define ST(OSLOT) do {                                                 \
        __builtin_nontemporal_store(acc[OSLOT], (v2f*)oq);                 \
        acc[OSLOT].x = 0.f; acc[OSLOT].y = 0.f;                           \
        oq += W_OUT; } while (0)

    #define STSKIP(OSLOT) do {                                             \
        if (q == 0) __builtin_nontemporal_store(acc[OSLOT], (v2f*)oq);     \
        acc[OSLOT].x = 0.f; acc[OSLOT].y = 0.f;                           \
        oq += W_OUT; } while (0)

    // ---- prologue staging: pairs 0,1,2 -> slots 0,1,2 ----
    STAGE(0); STAGE(1); STAGE(2);

    // m=0: rows 0,1 (partial ky)
    STAGE(3); WAITV(3);
    ROWD(0, 0, 0, 0, 0);
    ROWD(1, 0, 1, 0, 1);
    // m=1: rows 2,3
    STAGE(0); WAITV(3);
    ROWD(2, 1, 0, 0, 2);
    ROWD(3, 1, 1, 0, 3);
    // m=2: rows 4,5
    STAGE(1); WAITV(3);
    ROWD(4, 2, 0, 0, 4);
    ROWD(5, 2, 1, 0, 5);
    // m=3: rows 6,7; first stores o=0,1 (dup rows for q>0 -> skip)
    STAGE(2); WAITV(3);
    ROWD(6, 3, 0, 0, 6); STSKIP(0);
    ROWD(7, 3, 1, 0, 6); STSKIP(1);
    // m=4: rows 8,9
    STAGE(3); WAITV(3);
    ROWD(0, 0, 0, 0, 6); ST(2);
    ROWD(1, 0, 1, 0, 6); ST(3);
    // m=5: rows 10,11
    STAGE(0); WAITV(5);
    ROWD(2, 1, 0, 0, 6); ST(4);
    ROWD(3, 1, 1, 0, 6); ST(5);
    // m=6: rows 12,13
    STAGE(1); WAITV(7);
    ROWD(4, 2, 0, 0, 6); ST(6);
    ROWD(5, 2, 1, 0, 6); ST(7);

    // ---- steady: m=7..14 (2 reps x 4 macro-steps), vmcnt(9) counted ----
    for (int rep = 0; rep < 2; ++rep) {
        STAGE(2); WAITV(9);
        ROWD(6, 3, 0, 0, 6); ST(0);
        ROWD(7, 3, 1, 0, 6); ST(1);
        STAGE(3); WAITV(9);
        ROWD(0, 0, 0, 0, 6); ST(2);
        ROWD(1, 0, 1, 0, 6); ST(3);
        STAGE(0); WAITV(9);
        ROWD(2, 1, 0, 0, 6); ST(4);
        ROWD(3, 1, 1, 0, 6); ST(5);
        STAGE(1); WAITV(9);
        ROWD(4, 2, 0, 0, 6); ST(6);
        ROWD(5, 2, 1, 0, 6); ST(7);
    }

    // ---- tail: m=15..18 (last stage at m=15; decreasing counted waits) ----
    STAGE(2); WAITV(9);
    ROWD(6, 3, 0, 0, 6); ST(0);
    ROWD(7, 3, 1, 0, 6); ST(1);
    WAITV(8);
    ROWD(0, 0, 0, 1, 6); ST(2);
    ROWD(1, 0, 1, 2, 6); ST(3);
    WAITV(7);
    ROWD(2, 1, 0, 3, 6); ST(4);
    ROWD(3, 1, 1, 4, 6); ST(5);
    WAITV(6);
    ROWD(4, 2, 0, 5, 6); ST(6);
    ROWD(5, 2, 1, 6, 6); ST(7);

    #undef STAGE
    #undef WAITV
    #undef ROWD
    #undef ST
    #undef STSKIP
}

extern "C" void kernel_launch(void* const* d_in, const int* in_sizes, int n_in,
                              void* d_out, int out_size, void* d_ws, size_t ws_size,
                              hipStream_t stream) {
    const float* x = (const float*)d_in[0];
    const float* w = (const float*)d_in[1];
    float* out = (float*)d_out;

    // one block per image; 4 waves = 4 row-quarters
    dim3 grid(BATCH * CHAN, 1, 1);   // 4096 blocks
    dim3 block(256, 1, 1);
    dwconv7x7_kernel<<<grid, block, 0, stream>>>(x, w, out);
}